// Round 1
// baseline (997.371 us; speedup 1.0000x reference)
//
#include <hip/hip_runtime.h>

#define HID 256
#define TLEN 1024
#define BATCH 128

typedef _Float16 half2_t __attribute__((ext_vector_type(2)));

__device__ __forceinline__ float fexp2(float x) { return __builtin_amdgcn_exp2f(x); }
__device__ __forceinline__ float frcp(float x)  { return __builtin_amdgcn_rcpf(x); }
__device__ __forceinline__ float fast_sigmoid(float x) {
  return frcp(1.0f + fexp2(-1.442695040888963f * x));
}
__device__ __forceinline__ float fast_tanh(float x) {
  float e = fexp2(2.885390081777927f * x);
  return 1.0f - 2.0f * frcp(e + 1.0f);
}
__device__ __forceinline__ float dot2acc(half2_t a, half2_t b, float c) {
  return __builtin_amdgcn_fdot2(a, b, c, false);   // v_dot2_f32_f16
}

#if defined(__has_builtin) && __has_builtin(__builtin_amdgcn_sdot4)
#define SDOT4(a, b, c) __builtin_amdgcn_sdot4((int)(a), (int)(b), (c), false)
#else
__device__ __forceinline__ int SDOT4(int a, int b, int c) {
#pragma unroll
  for (int e = 0; e < 4; ++e)
    c += ((a << (24 - 8 * e)) >> 24) * ((b << (24 - 8 * e)) >> 24);
  return c;
}
#endif

// DPP (VALU pipe). Verified on this HW in earlier rounds.
#define DPP_ADD_F(var, ctrl, rmask)                                            \
  var += __builtin_bit_cast(float, __builtin_amdgcn_update_dpp(                \
      0, __builtin_bit_cast(int, var), (ctrl), (rmask), 0xf, true))

__device__ __forceinline__ float wave_sum63_f(float p) {
  DPP_ADD_F(p, 0x111, 0xf);
  DPP_ADD_F(p, 0x112, 0xf);
  DPP_ADD_F(p, 0x114, 0xf);
  DPP_ADD_F(p, 0x118, 0xf);
  DPP_ADD_F(p, 0x142, 0xa);
  DPP_ADD_F(p, 0x143, 0xc);   // -> lane63 has wave total
  return p;
}

// ---- prep: per-row i8 quant of W_hh (768x256), layout wq[row*16 + c]
// (row-contiguous so persistent thread r loads 16 consecutive uint4).
__global__ void quant_whh(const float* __restrict__ W_hh,
                          uint4* __restrict__ wq,
                          float* __restrict__ scales) {
  const int r = blockIdx.x * 256 + threadIdx.x;   // 0..767
  const float* row = W_hh + (size_t)r * HID;
  float amax = 0.0f;
  for (int k = 0; k < HID; ++k) amax = fmaxf(amax, fabsf(row[k]));
  amax = fmaxf(amax, 1e-20f);
  scales[r] = amax / 127.0f;
  const float inv = 127.0f / amax;
  for (int c = 0; c < 16; ++c) {
    unsigned w[4];
#pragma unroll
    for (int u = 0; u < 4; ++u) {
      unsigned bb = 0;
#pragma unroll
      for (int e = 0; e < 4; ++e) {
        int qv = (int)rintf(row[16 * c + 4 * u + e] * inv);
        bb |= (unsigned)(qv & 0xff) << (8 * e);
      }
      w[u] = bb;
    }
    wq[(size_t)r * 16 + c] = uint4{w[0], w[1], w[2], w[3]};
  }
}

// R14: gate-split persistent kernel. One block per batch element, 768 threads
// (12 waves, 3 waves/SIMD). Thread tid owns row tid of the 768x256 recurrent
// matvec: gate g = tid>>8 (0=r,1=z,2=n), dim d = tid&255. Only 16 uint4 of
// weights per thread -> fits the 168-VGPR budget at 3 waves/SIMD (no AGPR
// parking, no per-step unpark reads). Two barriers/step:
//   phase 1 (all): beta + momentum + 64-sdot burst; r/z waves write sigma->LDS
//   phase 2 (n-waves): r,z -> tanh -> h' -> i8 h -> float hWb partials (DPP)
// beta's hWb is now computed in FLOAT by the n-waves one step ahead (red4),
// removing the i8 Wb path + int DPP reduce + readlane from phase 1.
__global__
__attribute__((amdgpu_flat_work_group_size(768, 768)))
void momgru_persistent(const float* __restrict__ x,
                       const float* __restrict__ W_ih,
                       const float* __restrict__ b_ih,
                       const float* __restrict__ b_hh,
                       const float* __restrict__ Wb_x,
                       const float* __restrict__ Wb_h,
                       const float* __restrict__ b_beta,
                       const float* __restrict__ s_ptr,
                       const float* __restrict__ W_head,
                       const float* __restrict__ b_head,
                       const uint4* __restrict__ wq,
                       const float* __restrict__ scales,
                       float* __restrict__ out)  // [0,128) head, [128,128+B*T) betas
{
  const int b    = blockIdx.x;
  const int tid  = threadIdx.x;   // row r of [768 x 256]
  const int lane = tid & 63;
  const int wv   = tid >> 6;      // 0..11
  const int g    = tid >> 8;      // 0=r,1=z,2=n (wave-uniform)
  const int d    = tid & 255;     // hidden dim

  __shared__ __align__(16) unsigned hq[64];   // h_t as i8 (single buffer)
  __shared__ float  rz[2][256];               // r,z gate values
  __shared__ float4 red4;                     // hWb partials (bbeta folded in .x)
  __shared__ float  headred[4];

  // ---- weights: 16 uint4 per row, register-resident ----
  const uint4* wqt = wq + (size_t)tid * 16;
  uint4 w[16];
#pragma unroll
  for (int j = 0; j < 16; ++j) w[j] = wqt[j];

  // ---- per-thread constants (s pre-folded into input projection) ----
  const float sv = s_ptr[0];
  const half2_t wih2 = half2_t{(_Float16)(sv * W_ih[2 * tid]),
                               (_Float16)(sv * W_ih[2 * tid + 1])};
  const float bih = sv * b_ih[tid];
  const float bhh = b_hh[tid];
  const float sc  = scales[tid] * (1.0f / 127.0f);
  const half2_t wbx2 = half2_t{(_Float16)Wb_x[0], (_Float16)Wb_x[1]};  // uniform
  const float bbeta = b_beta[0];
  const float wbh   = Wb_h[d];    // used by n-waves

  // ---- init ----
  if (tid < 64) hq[tid] = 0u;
  if (tid == 0) red4 = make_float4(bbeta, 0.0f, 0.0f, 0.0f);
  float v = 0.0f, h_old = 0.0f;
  float* betas = out + BATCH;
  const float2* xg2 = reinterpret_cast<const float2*>(x + (size_t)b * TLEN * 2);
  float2 xv = xg2[0];
  __syncthreads();

  for (int t = 0; t < TLEN; ++t) {
    // ---- phase 1: beta (from float hWb partials) + momentum ----
    const float4 rr = red4;                         // uniform ds_read_b128
    const float hwb = (rr.x + rr.y) + (rr.z + rr.w);  // bbeta already folded
    const half2_t x2 = half2_t{(_Float16)xv.x, (_Float16)xv.y};
    xv = xg2[(t + 1 < TLEN) ? t + 1 : t];           // prefetch next x
    const float beta = fast_sigmoid(dot2acc(x2, wbx2, hwb));
    v = beta * v + dot2acc(x2, wih2, bih);
    if (tid == 0) betas[(size_t)b * TLEN + t] = beta;

    // ---- i8 matvec burst: a = <h_i8, W_row_i8>, 4 accumulators ----
    const int4* hb = reinterpret_cast<const int4*>(hq);   // 16 x int4, uniform
    int a0 = 0, a1 = 0, a2 = 0, a3 = 0;
#pragma unroll
    for (int c = 0; c < 4; ++c) {
      const int4 h0 = hb[4 * c + 0];
      const int4 h1 = hb[4 * c + 1];
      const int4 h2 = hb[4 * c + 2];
      const int4 h3 = hb[4 * c + 3];
      a0 = SDOT4(h0.x, w[4 * c + 0].x, a0);
      a1 = SDOT4(h1.x, w[4 * c + 1].x, a1);
      a2 = SDOT4(h2.x, w[4 * c + 2].x, a2);
      a3 = SDOT4(h3.x, w[4 * c + 3].x, a3);
      a0 = SDOT4(h0.y, w[4 * c + 0].y, a0);
      a1 = SDOT4(h1.y, w[4 * c + 1].y, a1);
      a2 = SDOT4(h2.y, w[4 * c + 2].y, a2);
      a3 = SDOT4(h3.y, w[4 * c + 3].y, a3);
      a0 = SDOT4(h0.z, w[4 * c + 0].z, a0);
      a1 = SDOT4(h1.z, w[4 * c + 1].z, a1);
      a2 = SDOT4(h2.z, w[4 * c + 2].z, a2);
      a3 = SDOT4(h3.z, w[4 * c + 3].z, a3);
      a0 = SDOT4(h0.w, w[4 * c + 0].w, a0);
      a1 = SDOT4(h1.w, w[4 * c + 1].w, a1);
      a2 = SDOT4(h2.w, w[4 * c + 2].w, a2);
      a3 = SDOT4(h3.w, w[4 * c + 3].w, a3);
    }
    const int a = (a0 + a1) + (a2 + a3);
    const float ga = fmaf((float)a, sc, bhh);       // hidden projection, this row

    if (g < 2) rz[g][d] = fast_sigmoid(v + ga);     // r,z -> LDS
    __syncthreads();

    // ---- phase 2 (n-waves only): n, h', quantize, next-step hWb partials ----
    if (g == 2) {
      const float r_ = rz[0][d];
      const float z_ = rz[1][d];
      const float n_ = fast_tanh(fmaf(r_, ga, v));
      h_old = fmaf(z_, h_old - n_, n_);             // (1-z)n + z h
      const int q = (int)rintf(h_old * 127.0f);
      reinterpret_cast<unsigned char*>(hq)[d] = (unsigned char)(q & 0xff);
      float p = h_old * wbh;                        // float hWb partial
      p = wave_sum63_f(p);
      if (lane == 63) {
        const float pv = (wv == 8) ? p + bbeta : p; // fold bbeta once
        reinterpret_cast<float*>(&red4)[wv - 8] = pv;
      }
    }
    __syncthreads();
  }

  // ---- head (h_T lives in the n-waves) ----
  if (g == 2) {
    float hp = h_old * W_head[d];
    hp = wave_sum63_f(hp);
    if (lane == 63) headred[wv - 8] = hp;
  }
  __syncthreads();
  if (tid == 0)
    out[b] = ((headred[0] + headred[1]) + (headred[2] + headred[3])) + b_head[0];
}

extern "C" void kernel_launch(void* const* d_in, const int* in_sizes, int n_in,
                              void* d_out, int out_size, void* d_ws, size_t ws_size,
                              hipStream_t stream) {
  const float* x      = (const float*)d_in[0];
  const float* W_ih   = (const float*)d_in[1];
  const float* W_hh   = (const float*)d_in[2];
  const float* b_ih   = (const float*)d_in[3];
  const float* b_hh   = (const float*)d_in[4];
  const float* Wb_x   = (const float*)d_in[5];
  const float* Wb_h   = (const float*)d_in[6];
  const float* b_beta = (const float*)d_in[7];
  const float* s      = (const float*)d_in[8];
  const float* W_head = (const float*)d_in[9];
  const float* b_head = (const float*)d_in[10];
  float* out = (float*)d_out;

  char* wsb = (char*)d_ws;
  uint4* wq     = (uint4*)wsb;                 // 768*16*16 = 196608 B
  float* scales = (float*)(wsb + 196608);      // 768*4 = 3072 B

  quant_whh<<<dim3(3), dim3(256), 0, stream>>>(W_hh, wq, scales);
  momgru_persistent<<<dim3(BATCH), dim3(768), 0, stream>>>(
      x, W_ih, b_ih, b_hh, Wb_x, Wb_h, b_beta, s, W_head, b_head,
      (const uint4*)wq, (const float*)scales, out);
}